// Round 5
// baseline (344.529 us; speedup 1.0000x reference)
//
#include <hip/hip_runtime.h>

// Problem: per-batch segment_sum over sorted segment ids.
// B=16, L=4096, H=768, fp32. out[b,j,:] = sum_{p: seg[b,p]==j} x[b,p,:].
// Sorted ids => token j's wordpieces are the contiguous range
// [lower_bound(seg_b, j), lower_bound(seg_b, j+1)).
//
// Round-5 structure: ONE kernel, 2048 blocks (= exactly one resident
// generation: 8 blocks/CU x 4 waves = 32 waves/CU from t=0 -- attacks the
// 57% OccupancyPercent measured on the 16384-block per-token variants).
// Each wave owns TT=8 consecutive tokens and processes them as 8 INDEPENDENT
// copies of the round-0-verified accumulate loop (no per-row flush branches,
// which cost +14us in rounds 2/3). Bounds: 9 ballot lower-bound searches
// sharing ONE step-1 probe (1+9 gathers per wave = 1.25/token, vs 3/token in
// round 0; no bounds pre-pass launch, which cost ~8us in round 4).
#define BB 16
#define LL 4096
#define H4 192    // 768 floats = 192 float4 per row
#define TT 8      // tokens per wave
#define LOG2T 3

// Round-0-verified 64-ary lower_bound over the sorted 4096-int row sb.
// v1 = sb[lane*64] (step-1 probe, shared across calls). Returns smallest p
// with sb[p] >= j (LL if none). Wave-collective: all 64 lanes participate.
__device__ __forceinline__ int lb64(const int* __restrict__ sb, int v1,
                                    int j, int lane) {
    unsigned long long m = __ballot(v1 >= j);
    if (m & 1ull) return 0;                       // sb[0] >= j
    int f = m ? (__ffsll(m) - 1) : 64;            // first 64-block >= j
    int base = ((f - 1) << 6) + 1;                // search (f-1)*64+1 .. f*64
    int p2 = base + lane;
    int v2 = (p2 < LL) ? sb[p2] : 0x7fffffff;     // sb[LL] := +inf
    unsigned long long m2 = __ballot(v2 >= j);    // lane 63 always eligible
    return base + __ffsll(m2) - 1;
}

__global__ __launch_bounds__(256) void segsum_persist_kernel(
    const float4* __restrict__ x, const int* __restrict__ seg,
    float4* __restrict__ out) {
    int gtid = blockIdx.x * blockDim.x + threadIdx.x;
    int wave = gtid >> 6;                    // 0 .. B*L/TT-1 (8192)
    int lane = gtid & 63;
    int b    = wave >> (12 - LOG2T);         // / (L/TT)
    int j0   = (wave & ((LL >> LOG2T) - 1)) << LOG2T;

    const int* __restrict__ sb = seg + ((size_t)b << 12);

    // ---- bounds for the 9 token boundaries j0..j0+8 (shared probe) ----
    int v1 = sb[lane << 6];
    int bound[TT + 1];
    #pragma unroll
    for (int i = 0; i <= TT; ++i)
        bound[i] = lb64(sb, v1, j0 + i, lane);   // static index after unroll

    // ---- 8 independent round-0 accumulate loops ----
    const float4* __restrict__ xb = x + (size_t)b * (LL * H4);
    float4* __restrict__ ob = out + ((size_t)(b << 12) + j0) * H4 + lane;

    #pragma unroll
    for (int i = 0; i < TT; ++i) {
        int s = bound[i];
        int e = bound[i + 1];
        float4 a0 = make_float4(0.f, 0.f, 0.f, 0.f);
        float4 a1 = a0, a2 = a0;
        for (int p = s; p < e; ++p) {
            const float4* row = xb + (size_t)p * H4 + lane;
            float4 v0 = row[0];
            float4 vA = row[64];
            float4 vB = row[128];
            a0.x += v0.x; a0.y += v0.y; a0.z += v0.z; a0.w += v0.w;
            a1.x += vA.x; a1.y += vA.y; a1.z += vA.z; a1.w += vA.w;
            a2.x += vB.x; a2.y += vB.y; a2.z += vB.z; a2.w += vB.w;
        }
        // every out row in the chunk written exactly once (poison-safe;
        // empty tokens get zeros)
        float4* orow = ob + (size_t)i * H4;
        orow[0]   = a0;
        orow[64]  = a1;
        orow[128] = a2;
    }
}

extern "C" void kernel_launch(void* const* d_in, const int* in_sizes, int n_in,
                              void* d_out, int out_size, void* d_ws, size_t ws_size,
                              hipStream_t stream) {
    const float* x   = (const float*)d_in[0];   // (B, L, H) fp32
    const int*   seg = (const int*)d_in[1];     // (B, L) int32, sorted per row
    float* out = (float*)d_out;                 // (B, L, H) fp32
    (void)d_ws; (void)ws_size;

    // B*L/TT = 8192 waves, 4 per 256-thread block -> 2048 blocks
    int nblocks = (BB * (LL >> LOG2T)) / 4;
    segsum_persist_kernel<<<nblocks, 256, 0, stream>>>(
        (const float4*)x, seg, (float4*)out);
}

// Round 6
// 328.911 us; speedup vs baseline: 1.0475x; 1.0475x over previous
//
#include <hip/hip_runtime.h>

// Problem: per-batch segment_sum over sorted segment ids.
// B=16, L=4096, H=768, fp32. out[b,j,:] = sum_{p: seg[b,p]==j} x[b,p,:].
// Sorted ids => token j's wordpieces are the contiguous range
// [lower_bound(seg_b, j), lower_bound(seg_b, j+1)).
//
// Round-6: the round-0 champion (one wave per token, in-wave 64-ary ballot
// search, plain stores -- empirically the best structure across 5 rounds:
// beats 8-token chunking by ~14us, NT stores by ~10us, table+prepass by
// ~4us) with ONE change: workgroup size 256 -> 1024. Same 65536 independent
// per-token waves, but packed into 4096 workgroups instead of 16384 -- 4x
// fewer dispatcher transactions. Attacks the measured 57% OccupancyPercent
// (16 VGPR / 0 LDS / nothing resource-bound => idle slots = dispatch/drain
// churn of ~1us-lifetime workgroups). Per-wave code is byte-identical.
#define BB 16
#define LL 4096
#define H4 192   // 768 floats = 192 float4 per row

__global__ __launch_bounds__(1024) void segsum_fused_kernel(
    const float4* __restrict__ x, const int* __restrict__ seg,
    float4* __restrict__ out) {
    int gtid = blockIdx.x * blockDim.x + threadIdx.x;
    int wave = gtid >> 6;          // 0 .. B*L-1
    int lane = gtid & 63;
    int b = wave >> 12;            // / L
    int j = wave & (LL - 1);       // % L

    const int* __restrict__ sb = seg + ((size_t)b << 12);

    // step-1 probe (whole row, stride 64) — shared by both bounds
    int v1 = sb[lane << 6];
    unsigned long long ms = __ballot(v1 >= j);       // for lower_bound(j)
    unsigned long long me = __ballot(v1 > j);        // for lower_bound(j+1)

    int s, e;
    if (ms & 1ull) {
        s = 0;                     // seg[0] >= j
    } else {
        int f = ms ? (__ffsll((unsigned long long)ms) - 1) : 64;
        int base = ((f - 1) << 6) + 1;               // search (f-1)*64+1 .. f*64
        int p2 = base + lane;
        int v2 = (p2 < LL) ? sb[p2] : 0x7fffffff;    // seg[L] := +inf
        unsigned long long m2 = __ballot(v2 >= j);   // lane 63 always eligible
        s = base + __ffsll(m2) - 1;
    }
    if (me & 1ull) {
        e = 0;
    } else {
        int f = me ? (__ffsll((unsigned long long)me) - 1) : 64;
        int base = ((f - 1) << 6) + 1;
        int p2 = base + lane;
        int v2 = (p2 < LL) ? sb[p2] : 0x7fffffff;
        unsigned long long m2 = __ballot(v2 > j);
        e = base + __ffsll(m2) - 1;
    }

    float4 a0 = make_float4(0.f, 0.f, 0.f, 0.f);
    float4 a1 = a0, a2 = a0;

    const float4* xb = x + (size_t)b * LL * H4;
    for (int p = s; p < e; ++p) {
        const float4* row = xb + (size_t)p * H4 + lane;
        float4 v0 = row[0];
        float4 vA = row[64];
        float4 vB = row[128];
        a0.x += v0.x; a0.y += v0.y; a0.z += v0.z; a0.w += v0.w;
        a1.x += vA.x; a1.y += vA.y; a1.z += vA.z; a1.w += vA.w;
        a2.x += vB.x; a2.y += vB.y; a2.z += vB.z; a2.w += vB.w;
    }

    float4* orow = out + (size_t)wave * H4 + lane;
    orow[0]   = a0;
    orow[64]  = a1;
    orow[128] = a2;
}

extern "C" void kernel_launch(void* const* d_in, const int* in_sizes, int n_in,
                              void* d_out, int out_size, void* d_ws, size_t ws_size,
                              hipStream_t stream) {
    const float* x   = (const float*)d_in[0];   // (B, L, H) fp32
    const int*   seg = (const int*)d_in[1];     // (B, L) int32, sorted per row
    float* out = (float*)d_out;                 // (B, L, H) fp32
    (void)d_ws; (void)ws_size;

    // B*L waves total, 16 waves per 1024-thread block -> 4096 blocks
    int nblocks = (BB * LL) / 16;
    segsum_fused_kernel<<<nblocks, 1024, 0, stream>>>(
        (const float4*)x, seg, (float4*)out);
}